// Round 14
// baseline (199.190 us; speedup 1.0000x reference)
//
#include <hip/hip_runtime.h>
#include <hip/hip_cooperative_groups.h>
#include <math.h>

// out = gelu(rowmean(x@W^T - subtract) + logN) + x
// rowmean(x@W^T)[m] = (1/N) * dot(x[m,:], colsum(W)).  No GEMM needed.
//
// R14: single cooperative kernel, grid sized from MEASURED occupancy
// (R13 failed: hard-coded 1024 blocks > co-residency limit, launch error
// was swallowed and out stayed zero).
// Phase 0: 256 worker blocks accumulate W row-chunks into registers;
//          block 0 also zeroes wsum, block 1 also computes submean.
// sync -> Phase B: atomicAdd partials into wsum.
// sync -> Phase C: R10 fused body (wave-per-row, 16 f4 register-resident,
//          plain loads + NT stores), grid-stride over rows.

namespace cg = cooperative_groups;

typedef float f4 __attribute__((ext_vector_type(4)));

#define TPB 256
#define WORKERS 256

__global__ __launch_bounds__(TPB, 2) void mono_kernel(
    const float* __restrict__ x, const float* __restrict__ w,
    const float* __restrict__ sub, float* __restrict__ out,
    float* __restrict__ wsum, float* __restrict__ submean,
    int M, int K, int N, float logN, float invN) {
    cg::grid_group grid = cg::this_grid();
    const int tid = threadIdx.x;
    const int bid = blockIdx.x;
    const int K4 = K >> 2;                 // 1024 f4 per row
    __shared__ float sd[4];

    // ---------------- Phase 0 ----------------
    f4 part0 = (f4)(0.f), part1 = (f4)(0.f), part2 = (f4)(0.f), part3 = (f4)(0.f);
    const bool worker = bid < WORKERS;
    if (worker) {
        if (bid == 0) {
            // Zero wsum (1024 f4 / 256 threads = 4 each).
            f4* wz = (f4*)wsum;
            #pragma unroll
            for (int j = 0; j < 4; ++j) wz[j * TPB + tid] = (f4)(0.f);
        } else if (bid == 1) {
            // submean = mean(subtract).
            float acc = 0.f;
            for (int i = tid; i < N; i += TPB) acc += sub[i];
            #pragma unroll
            for (int off = 32; off > 0; off >>= 1) acc += __shfl_down(acc, off, 64);
            if ((tid & 63) == 0) sd[tid >> 6] = acc;
            __syncthreads();
            if (tid == 0) submean[0] = (sd[0] + sd[1] + sd[2] + sd[3]) * invN;
        }
        // W row-chunk -> register partials.
        const int wrows = N / WORKERS;     // 16
        const f4* w4 = (const f4*)w;
        for (int r = 0; r < wrows; ++r) {
            const f4* wr = w4 + (size_t)(bid * wrows + r) * K4;
            part0 += __builtin_nontemporal_load(&wr[0 * TPB + tid]);
            part1 += __builtin_nontemporal_load(&wr[1 * TPB + tid]);
            part2 += __builtin_nontemporal_load(&wr[2 * TPB + tid]);
            part3 += __builtin_nontemporal_load(&wr[3 * TPB + tid]);
        }
    }

    grid.sync();

    // ---------------- Phase B: atomics into wsum ----------------
    if (worker) {
        #pragma unroll
        for (int j = 0; j < 4; ++j) {
            const f4 p = (j == 0) ? part0 : (j == 1) ? part1 : (j == 2) ? part2 : part3;
            float* dst = wsum + (size_t)(j * TPB + tid) * 4;
            atomicAdd(dst + 0, p.x);
            atomicAdd(dst + 1, p.y);
            atomicAdd(dst + 2, p.z);
            atomicAdd(dst + 3, p.w);
        }
    }

    grid.sync();

    // ---------------- Phase C: fused rows (R10 body) ----------------
    const float sm = submean[0];
    const int lane = tid & 63;
    const int gw = bid * 4 + (tid >> 6);
    const int nwaves = gridDim.x * 4;
    const f4* ws4 = (const f4*)wsum;

    for (int row = gw; row < M; row += nwaves) {
        const f4* x4 = (const f4*)(x + (size_t)row * K);

        f4 xv[16];
        f4 acc = (f4)(0.f);
        #pragma unroll
        for (int j = 0; j < 16; ++j) {
            const int idx = j * 64 + lane;     // coalesced per wave
            const f4 xx = x4[idx];             // plain load (L2/L3 path)
            const f4 ww = ws4[idx];            // L1-resident (16 KB)
            xv[j] = xx;
            acc += xx * ww;                    // 4 independent chains
        }
        float dot = (acc.x + acc.y) + (acc.z + acc.w);

        #pragma unroll
        for (int off = 1; off < 64; off <<= 1) dot += __shfl_xor(dot, off, 64);

        const float c = dot * invN - sm + logN;
        const float t = 0.7978845608028654f * fmaf(0.044715f * c, c * c, c);
        const float g = 0.5f * c * (1.f + t / (fabsf(t) + 1.f));

        f4* o4 = (f4*)(out + (size_t)row * K);
        #pragma unroll
        for (int j = 0; j < 16; ++j)
            __builtin_nontemporal_store(xv[j] + (f4)(g), &o4[j * 64 + lane]);
    }
}

extern "C" void kernel_launch(void* const* d_in, const int* in_sizes, int n_in,
                              void* d_out, int out_size, void* d_ws, size_t ws_size,
                              hipStream_t stream) {
    const float* x   = (const float*)d_in[0];
    const float* w   = (const float*)d_in[1];
    const float* sub = (const float*)d_in[2];
    float* out = (float*)d_out;

    int N = in_sizes[2];                  // 4096
    int K = in_sizes[1] / N;              // 4096
    int M = in_sizes[0] / K;              // 16384

    float* wsum    = (float*)d_ws;        // K floats
    float* submean = wsum + K;            // 1 float

    float logN = logf((float)N);
    float invN = 1.0f / (float)N;

    // Size the cooperative grid from MEASURED occupancy (R13 lesson).
    int occ = 0;
    (void)hipOccupancyMaxActiveBlocksPerMultiprocessor(&occ, mono_kernel, TPB, 0);
    if (occ < 1) occ = 1;
    int ncu = 0;
    (void)hipDeviceGetAttribute(&ncu, hipDeviceAttributeMultiprocessorCount, 0);
    if (ncu < 1) ncu = 256;
    int nblk = occ * ncu;
    if (nblk > 1024) nblk = 1024;
    if (nblk < WORKERS) nblk = WORKERS;   // phase 0 needs 256 blocks

    void* args[] = {(void*)&x, (void*)&w, (void*)&sub, (void*)&out,
                    (void*)&wsum, (void*)&submean,
                    (void*)&M, (void*)&K, (void*)&N, (void*)&logN, (void*)&invN};
    (void)hipLaunchCooperativeKernel((void*)mono_kernel, dim3(nblk), dim3(TPB),
                                     args, 0, stream);
}

// Round 15
// 130.618 us; speedup vs baseline: 1.5250x; 1.5250x over previous
//
#include <hip/hip_runtime.h>
#include <math.h>

// out = gelu(rowmean(x@W^T - subtract) + logN) + x
// rowmean(x@W^T)[m] = (1/N) * dot(x[m,:], colsum(W)).  No GEMM needed.
//
// R15 = R10 verbatim (measured best: 131.26 us).  Wave-per-row, 16 f4/lane
// register-resident x, plain loads + NT stores, 4 independent FMA chains.
// Reverting from the R13/R14 cooperative experiment (refuted: 199 us).

typedef float f4 __attribute__((ext_vector_type(4)));

// Kernel A: wsum[k] = sum_n W[n,k] (atomics over row-chunks).
// Last grid.y slice (blockIdx.x==0) also computes submean = mean(subtract).
__global__ __launch_bounds__(256) void colsum_kernel(
    const float* __restrict__ w, const float* __restrict__ sub,
    float* __restrict__ wsum, float* __restrict__ submean,
    int N, int K, int rows_per_block, float invN) {
    if (blockIdx.y == gridDim.y - 1) {
        if (blockIdx.x != 0) return;
        float acc = 0.f;
        for (int i = threadIdx.x; i < N; i += 256) acc += sub[i];
        #pragma unroll
        for (int off = 32; off > 0; off >>= 1) acc += __shfl_down(acc, off, 64);
        __shared__ float sd[4];
        if ((threadIdx.x & 63) == 0) sd[threadIdx.x >> 6] = acc;
        __syncthreads();
        if (threadIdx.x == 0) submean[0] = (sd[0] + sd[1] + sd[2] + sd[3]) * invN;
        return;
    }
    const int K4 = K >> 2;
    const int col4 = blockIdx.x * blockDim.x + threadIdx.x;
    if (col4 >= K4) return;
    const int row0 = blockIdx.y * rows_per_block;
    int row1 = row0 + rows_per_block;
    if (row1 > N) row1 = N;
    const f4* w4 = (const f4*)w;
    f4 acc = (f4)(0.f);
    for (int n = row0; n < row1; ++n) {
        acc += __builtin_nontemporal_load(&w4[(size_t)n * K4 + col4]);
    }
    float* dst = wsum + (size_t)col4 * 4;
    atomicAdd(dst + 0, acc.x);
    atomicAdd(dst + 1, acc.y);
    atomicAdd(dst + 2, acc.z);
    atomicAdd(dst + 3, acc.w);
}

// Kernel B: one WAVE per row, 16 float4/lane register-resident.
// Plain x loads, NT stores, elementwise f4 accumulator (4 indep chains).
__global__ __launch_bounds__(256) void fused_row_kernel(
    const float* __restrict__ x, const float* __restrict__ wsum,
    const float* __restrict__ submean_p, float* __restrict__ out,
    int M, int K, float logN, float invN) {
    const int lane = threadIdx.x & 63;
    const int row = blockIdx.x * 4 + (threadIdx.x >> 6);
    if (row >= M) return;
    const f4* x4 = (const f4*)(x + (size_t)row * K);
    const f4* ws4 = (const f4*)wsum;

    f4 xv[16];
    f4 acc = (f4)(0.f);
    #pragma unroll
    for (int j = 0; j < 16; ++j) {
        const int idx = j * 64 + lane;               // coalesced per wave
        const f4 xx = x4[idx];                       // plain load (L2/L3 path)
        const f4 ww = ws4[idx];                      // L1-resident (16 KB)
        xv[j] = xx;
        acc += xx * ww;                              // 4 independent chains
    }
    float dot = (acc.x + acc.y) + (acc.z + acc.w);

    #pragma unroll
    for (int off = 1; off < 64; off <<= 1) dot += __shfl_xor(dot, off, 64);

    const float c = dot * invN - submean_p[0] + logN;
    const float t = 0.7978845608028654f * fmaf(0.044715f * c, c * c, c);
    const float g = 0.5f * c * (1.f + t / (fabsf(t) + 1.f));

    f4* o4 = (f4*)(out + (size_t)row * K);
    #pragma unroll
    for (int j = 0; j < 16; ++j) {
        const int idx = j * 64 + lane;
        __builtin_nontemporal_store(xv[j] + (f4)(g), &o4[idx]);  // NT store
    }
}

extern "C" void kernel_launch(void* const* d_in, const int* in_sizes, int n_in,
                              void* d_out, int out_size, void* d_ws, size_t ws_size,
                              hipStream_t stream) {
    const float* x   = (const float*)d_in[0];
    const float* w   = (const float*)d_in[1];
    const float* sub = (const float*)d_in[2];
    float* out = (float*)d_out;

    const int N = in_sizes[2];            // 4096
    const int K = in_sizes[1] / N;        // 4096
    const int M = in_sizes[0] / K;        // 16384

    float* wsum    = (float*)d_ws;        // K floats
    float* submean = wsum + K;            // 1 float

    (void)hipMemsetAsync(d_ws, 0, (size_t)(K + 1) * sizeof(float), stream);

    const int K4 = K / 4;
    const int rows_per_block = 16;
    dim3 gA((K4 + 255) / 256, N / rows_per_block + 1);
    colsum_kernel<<<gA, 256, 0, stream>>>(w, sub, wsum, submean,
                                          N, K, rows_per_block, 1.0f / (float)N);

    fused_row_kernel<<<M / 4, 256, 0, stream>>>(
        x, wsum, submean, out, M, K, logf((float)N), 1.0f / (float)N);
}